// Round 10
// baseline (523.458 us; speedup 1.0000x reference)
//
#include <hip/hip_runtime.h>
#include <cstdint>
#include <cstddef>

#define NP    8500   // priors
#define BS    32     // batch
#define NGT   128    // gt boxes
#define NCLS  80     // classes
#define TOPKK 10

typedef unsigned long long u64;
typedef unsigned int u32;

static __device__ __forceinline__ float iou_prec(const float4 a, const float4 b) {
  float area_a = (a.z - a.x) * (a.w - a.y);
  float area_b = (b.z - b.x) * (b.w - b.y);
  float tlx = fmaxf(a.x, b.x), tly = fmaxf(a.y, b.y);
  float brx = fminf(a.z, b.z), bry = fminf(a.w, b.w);
  float ww = fmaxf(brx - tlx, 0.f), hh = fmaxf(bry - tly, 0.f);
  float inter = ww * hh;
  return inter / (area_a + area_b - inter + 1e-16f);
}

static __device__ __forceinline__ float iou_fast(const float4 a, const float4 b) {
  float area_a = (a.z - a.x) * (a.w - a.y);
  float area_b = (b.z - b.x) * (b.w - b.y);
  float tlx = fmaxf(a.x, b.x), tly = fmaxf(a.y, b.y);
  float brx = fminf(a.z, b.z), bry = fminf(a.w, b.w);
  float ww = fmaxf(brx - tlx, 0.f), hh = fmaxf(bry - tly, 0.f);
  float inter = ww * hh;
  return __fdividef(inter, area_a + area_b - inter + 1e-16f);
}

static __device__ __forceinline__ float clampp(float p) {
  return fminf(fmaxf(p, 1e-7f), 1.0f - 1e-7f);
}

static __device__ __forceinline__ float wlog(float p) {
  return __logf((1.0f - p) / p);
}

static __device__ __forceinline__ u64 shflxor_u64(u64 v, int mask) {
  int lo = __shfl_xor((int)(u32)(v & 0xffffffffull), mask, 64);
  int hi = __shfl_xor((int)(u32)(v >> 32), mask, 64);
  return ((u64)(u32)hi << 32) | (u32)lo;
}

static __device__ __forceinline__ u32 f2u_mono(float f) {
  u32 b = __float_as_uint(f);
  return b ^ ((b & 0x80000000u) ? 0xffffffffu : 0x80000000u);
}

// ---------------- kernel 1: masks + negsum + transposed cls-cost rows ----------------
__global__ __launch_bounds__(256) void k_prep(
    const float* __restrict__ priors, const float* __restrict__ gtb,
    const float* __restrict__ clsp,
    float* __restrict__ negsum, unsigned char* __restrict__ valid,
    u64* __restrict__ inboth, float* __restrict__ ccostT)
{
  __shared__ float4 sg[NGT];
  const int b = blockIdx.y;
  const int tid = threadIdx.x;
  if (tid < NGT) sg[tid] = reinterpret_cast<const float4*>(gtb + (size_t)b * NGT * 4)[tid];
  __syncthreads();
  const int n = blockIdx.x * 256 + tid;
  if (n >= NP) return;
  const float4 pr = reinterpret_cast<const float4*>(priors)[n];
  const float cx = pr.x, cy = pr.y, sw = pr.z, sh = pr.w;
  u64 m0 = 0, m1 = 0;
  bool anyv = false;
  const float CR = 2.5f;
  for (int g = 0; g < NGT; ++g) {
    float4 gb = sg[g];
    float ib = fminf(fminf(cx - gb.x, cy - gb.y), fminf(gb.z - cx, gb.w - cy));
    bool in_box = ib > 0.f;
    float gcx = (gb.x + gb.z) * 0.5f, gcy = (gb.y + gb.w) * 0.5f;
    float ic = fminf(fminf(cx - (gcx - CR * sw), cy - (gcy - CR * sh)),
                     fminf(gcx + CR * sw - cx, gcy + CR * sh - cy));
    bool in_ctr = ic > 0.f;
    anyv |= (in_box | in_ctr);
    if (in_box && in_ctr) {
      if (g < 64) m0 |= 1ull << g; else m1 |= 1ull << (g - 64);
    }
  }
  const size_t idx = (size_t)b * NP + n;
  valid[idx] = anyv ? 1 : 0;
  inboth[idx * 2] = m0;
  inboth[idx * 2 + 1] = m1;

  const float4* row4 = reinterpret_cast<const float4*>(clsp + idx * NCLS);
  float s = 0.f;
  #pragma unroll 5
  for (int i = 0; i < NCLS / 4; ++i) {
    float4 p4 = row4[i];
    float q0 = 1.f - clampp(p4.x), q1 = 1.f - clampp(p4.y);
    float q2 = 1.f - clampp(p4.z), q3 = 1.f - clampp(p4.w);
    s -= __logf((q0 * q1) * (q2 * q3));
  }
  negsum[idx] = s;

  #pragma unroll 5
  for (int i = 0; i < NCLS / 4; ++i) {
    float4 p4 = row4[i];
    float w0 = wlog(clampp(p4.x)), w1 = wlog(clampp(p4.y));
    float w2 = wlog(clampp(p4.z)), w3 = wlog(clampp(p4.w));
    const size_t base = ((size_t)b * NCLS + i * 4) * NP + n;
    ccostT[base]          = s + w0;
    ccostT[base + NP]     = s + w1;
    ccostT[base + 2 * NP] = s + w2;
    ccostT[base + 3 * NP] = s + w3;
  }
}

// ---------------- kernel 2: threshold-gated exact top-k (one wave per column) ----
// No private arrays (they demote to scratch: r4/r5 profiles). Candidates passing a
// wave-uniform threshold are compacted into LDS via ballot+prefix; a wave-parallel
// 10-round shuffle extract rebuilds exact top-10 + tightens the threshold.
#define CAND_CAP 128
#define CAND_TRIG 48
__global__ __launch_bounds__(64, 4) void k_assign(
    const float* __restrict__ dec, const float* __restrict__ gtb,
    const int* __restrict__ gtl,
    const unsigned char* __restrict__ valid,
    const u64* __restrict__ inboth, const float* __restrict__ ccostT,
    u64* __restrict__ match)
{
  __shared__ float ibuf[CAND_CAP];
  __shared__ u64  kbuf[CAND_CAP];
  __shared__ float cur_i[TOPKK];
  __shared__ u64  cur_k[TOPKK];

  // XCD-aware remap: 4096 blocks, 8 XCDs -> XCD x owns images [4x, 4x+4)
  const int wid = (int)((blockIdx.x & 7) * (gridDim.x >> 3) + (blockIdx.x >> 3));
  const int lane = threadIdx.x;
  const int b = wid >> 7;      // /NGT
  const int g = wid & 127;     // %NGT
  const float4 gb = reinterpret_cast<const float4*>(gtb)[b * NGT + g];
  const int l = gtl[b * NGT + g];
  const float4* decb = reinterpret_cast<const float4*>(dec) + (size_t)b * NP;
  const unsigned char* valb = valid + (size_t)b * NP;
  const u64* inbb = inboth + (size_t)b * NP * 2 + (g >> 6);
  const float* ccrow = ccostT + ((size_t)b * NCLS + l) * NP;
  const u64 gbit = 1ull << (g & 63);
  const u64 lanemask_lt = (1ull << lane) - 1ull;

  float taui = -1.f;      // current 10th-largest masked iou (wave-uniform)
  u64  tauk = ~0ull;      // current 10th-smallest cost key (wave-uniform)
  int icnt = 0, kcnt = 0;
  bool merged_i = false, merged_k = false;

  auto merge_i = [&]() {
    if (merged_i && lane == 0) {
      #pragma unroll
      for (int r = 0; r < TOPKK; ++r) ibuf[icnt + r] = cur_i[r];
    }
    int total = icnt + (merged_i ? TOPKK : 0);
    __threadfence_block();
    float c0 = (lane < total) ? ibuf[lane] : -3.4e38f;
    float c1 = (64 + lane < total) ? ibuf[64 + lane] : -3.4e38f;
    #pragma unroll
    for (int r = 0; r < TOPKK; ++r) {
      float cm = fmaxf(c0, c1);
      float mr = cm;
      #pragma unroll
      for (int off = 32; off; off >>= 1) mr = fmaxf(mr, __shfl_xor(mr, off, 64));
      u64 bal = __ballot(cm == mr);
      int win = __ffsll(bal) - 1;
      if (lane == win) { if (c0 == mr) c0 = -3.4e38f; else c1 = -3.4e38f; }
      if (lane == 0) cur_i[r] = mr;
      taui = mr;
    }
    icnt = 0; merged_i = true;
  };
  auto merge_k = [&]() {
    if (merged_k && lane == 0) {
      #pragma unroll
      for (int r = 0; r < TOPKK; ++r) kbuf[kcnt + r] = cur_k[r];
    }
    int total = kcnt + (merged_k ? TOPKK : 0);
    __threadfence_block();
    u64 c0 = (lane < total) ? kbuf[lane] : ~0ull;
    u64 c1 = (64 + lane < total) ? kbuf[64 + lane] : ~0ull;
    #pragma unroll
    for (int r = 0; r < TOPKK; ++r) {
      u64 cm = (c0 < c1) ? c0 : c1;
      u64 mr = cm;
      #pragma unroll
      for (int off = 32; off; off >>= 1) {
        u64 o = shflxor_u64(mr, off);
        if (o < mr) mr = o;
      }
      u64 bal = __ballot(cm == mr);
      int win = __ffsll(bal) - 1;
      if (lane == win) { if (c0 == mr) c0 = ~0ull; else c1 = ~0ull; }
      if (lane == 0) cur_k[r] = mr;
      tauk = mr;
    }
    kcnt = 0; merged_k = true;
  };

  for (int base = 0; base < NP; base += 64) {
    const int n0 = base + lane;
    const int n = (n0 < NP) ? n0 : (NP - 1);
    const bool inrange = (n0 < NP);
    const float4 db = decb[n];
    const bool vn = valb[n] != 0;
    const float iou = iou_fast(db, gb);
    const float v = vn ? iou : 0.f;

    // phase-1 candidate: masked iou above threshold
    bool ci = inrange & (v > taui);
    u64 bal = __ballot(ci);
    if (ci) ibuf[icnt + __popcll(bal & lanemask_lt)] = v;
    icnt += (int)__popcll(bal);

    // phase-2 candidate: cost key below threshold
    float c = fmaf(-3.f, __logf(iou + 1e-8f), ccrow[n]);
    const bool inb = ((inbb[2 * (size_t)n] & gbit) != 0);
    c += inb ? 0.f : 1e5f;
    c += vn ? 0.f : 1e8f;
    const u64 key = ((u64)f2u_mono(c) << 32) | (u32)n;
    bool ck = inrange & (key < tauk);
    bal = __ballot(ck);
    if (ck) kbuf[kcnt + __popcll(bal & lanemask_lt)] = key;
    kcnt += (int)__popcll(bal);

    if (icnt > CAND_TRIG) merge_i();
    if (kcnt > CAND_TRIG) merge_k();
  }
  if (icnt > 0) merge_i();
  if (kcnt > 0) merge_k();
  __threadfence_block();

  // dyn_k = clamp(floor(sum top-10 ious), 1, 10)
  float sum = 0.f;
  #pragma unroll
  for (int r = 0; r < TOPKK; ++r) sum += cur_i[r];
  int dynk = (int)sum;
  if (dynk < 1) dynk = 1;
  if (dynk > TOPKK) dynk = TOPKK;

  if (lane < dynk) {
    u32 nn = (u32)(cur_k[lane] & 0xffffffffu);
    atomicOr(&match[((size_t)b * NP + nn) * 2 + (g >> 6)], gbit);
  }
}

// ---------------- kernel 3: fused match-resolve + VFL/GIoU/DFL ----------------
__global__ __launch_bounds__(256) void k_postloss(
    const float* __restrict__ priors, const float* __restrict__ dec,
    const float* __restrict__ clsp, const float* __restrict__ regp,
    const float* __restrict__ gtb, const int* __restrict__ gtl,
    const float* __restrict__ negsum, const unsigned char* __restrict__ valid,
    const u64* __restrict__ inboth, const u64* __restrict__ match,
    float* __restrict__ p_vfl, float* __restrict__ p_gi, float* __restrict__ p_df,
    float* __restrict__ p_np, float* __restrict__ p_ns)
{
  __shared__ float4 sg[NGT];
  __shared__ int sl[NGT];
  const int b = blockIdx.y;
  const int tid = threadIdx.x;
  if (tid < NGT) {
    sg[tid] = reinterpret_cast<const float4*>(gtb + (size_t)b * NGT * 4)[tid];
    sl[tid] = gtl[b * NGT + tid];
  }
  __syncthreads();
  const int n = blockIdx.x * 256 + tid;
  float ts = 0.f, fgf = 0.f, vfl = 0.f, gi = 0.f, df = 0.f;
  if (n < NP) {
    const size_t idx = (size_t)b * NP + n;
    const float* row = clsp + idx * NCLS;
    u64 m0 = match[idx * 2], m1 = match[idx * 2 + 1];
    int pop = __popcll(m0) + __popcll(m1);
    int mg = 0;
    float4 db;
    if (pop > 0) {
      fgf = 1.f;
      db = reinterpret_cast<const float4*>(dec)[idx];
      if (pop == 1) {
        mg = m0 ? (__ffsll(m0) - 1) : (64 + __ffsll(m1) - 1);
      } else {
        // row-argmin over ALL GTs; contiguous clsp row (L1) + LDS gtb/gtl
        bool vn = valid[idx] != 0;
        u64 ib0 = inboth[idx * 2], ib1 = inboth[idx * 2 + 1];
        float nsv = negsum[idx];
        float bc = 3.4e38f;
        for (int gg = 0; gg < NGT; ++gg) {
          float base = nsv + wlog(clampp(row[sl[gg]]));
          bool inb = (((gg < 64) ? (ib0 >> gg) : (ib1 >> (gg - 64))) & 1ull) != 0;
          float iou = iou_fast(db, sg[gg]);
          float c = fmaf(-3.f, __logf(iou + 1e-8f), base);
          c += inb ? 0.f : 1e5f;
          c += vn ? 0.f : 1e8f;
          if (c < bc) { bc = c; mg = gg; }
        }
      }
      ts = iou_prec(db, sg[mg]);
    }

    // ---- VFL (background for all classes; fg replaces one term) ----
    const float4* row4 = reinterpret_cast<const float4*>(row);
    #pragma unroll 5
    for (int i = 0; i < NCLS / 4; ++i) {
      float4 p4 = row4[i];
      float ps[4] = {p4.x, p4.y, p4.z, p4.w};
      #pragma unroll
      for (int j = 0; j < 4; ++j) {
        float p = clampp(ps[j]);
        vfl += (-__logf(1.f - p)) * (0.75f * p * p);
      }
    }
    if (ts > 0.f) {
      const int lbl = sl[mg];
      float p = clampp(row[lbl]);
      float l1 = __logf(1.f - p);
      vfl -= (-l1) * (0.75f * p * p);
      vfl += (-(ts * __logf(p) + (1.f - ts) * l1)) * ts;

      const float4 ab = sg[mg];
      {
        float tlx = fmaxf(db.x, ab.x), tly = fmaxf(db.y, ab.y);
        float brx = fminf(db.z, ab.z), bry = fminf(db.w, ab.w);
        float iw = fmaxf(brx - tlx, 0.f), ih = fmaxf(bry - tly, 0.f);
        float inter = iw * ih;
        float ap = fmaxf(db.z - db.x, 0.f) * fmaxf(db.w - db.y, 0.f);
        float at = fmaxf(ab.z - ab.x, 0.f) * fmaxf(ab.w - ab.y, 0.f);
        float uni = ap + at - inter;
        float iou = inter / (uni + 1e-16f);
        float ctlx = fminf(db.x, ab.x), ctly = fminf(db.y, ab.y);
        float cbrx = fmaxf(db.z, ab.z), cbry = fmaxf(db.w, ab.w);
        float cw = fmaxf(cbrx - ctlx, 0.f), ch = fmaxf(cbry - ctly, 0.f);
        float ac = cw * ch;
        float gl = 1.f - (iou - (ac - uni) / (ac + 1e-16f));
        gi = gl * ts;
      }
      {
        const float4 pr = reinterpret_cast<const float4*>(priors)[n];
        const float s = pr.z;
        float dv[4] = {(pr.x - ab.x) / s, (pr.y - ab.y) / s,
                       (ab.z - pr.x) / s, (ab.w - pr.y) / s};
        const float* rrow = regp + idx * 32;
        float ce_sum = 0.f;
        #pragma unroll
        for (int side = 0; side < 4; ++side) {
          float tv = fminf(fmaxf(dv[side], 0.f), 6.9f);
          int tl_ = (int)tv;
          int tr_ = tl_ + 1; if (tr_ > 7) tr_ = 7;
          float wl = (float)(tl_ + 1) - tv;
          float wr = tv - (float)tl_;
          const float* lg = rrow + side * 8;
          float mx = lg[0];
          #pragma unroll
          for (int i = 1; i < 8; ++i) mx = fmaxf(mx, lg[i]);
          float se = 0.f;
          #pragma unroll
          for (int i = 0; i < 8; ++i) se += __expf(lg[i] - mx);
          float lse = __logf(se);
          float lp_tl = lg[tl_] - mx - lse;
          float lp_tr = lg[tr_] - mx - lse;
          ce_sum += -(lp_tl * wl + lp_tr * wr);
        }
        df = ce_sum * ts;
      }
    }
  }
  __shared__ float red[256];
  float acc[5] = {vfl, gi, df, fgf, ts};
  float out5[5];
  #pragma unroll
  for (int a = 0; a < 5; ++a) {
    __syncthreads();
    red[tid] = acc[a]; __syncthreads();
    for (int s = 128; s > 0; s >>= 1) { if (tid < s) red[tid] += red[tid + s]; __syncthreads(); }
    out5[a] = red[0];
  }
  if (tid == 0) {
    int blk = blockIdx.y * gridDim.x + blockIdx.x;
    p_vfl[blk] = out5[0];
    p_gi[blk]  = out5[1];
    p_df[blk]  = out5[2];
    p_np[blk]  = out5[3];
    p_ns[blk]  = out5[4];
  }
}

// ---------------- kernel 4: final reduction ----------------
__global__ __launch_bounds__(256) void k_final(
    const float* __restrict__ p_vfl, const float* __restrict__ p_gi,
    const float* __restrict__ p_df, const float* __restrict__ p_np,
    const float* __restrict__ p_ns, float* __restrict__ out, int nb)
{
  __shared__ double red[256];
  const float* arrs[5] = {p_vfl, p_gi, p_df, p_np, p_ns};
  double sums[5];
  for (int a = 0; a < 5; ++a) {
    double s = 0.0;
    for (int i = threadIdx.x; i < nb; i += 256) s += (double)arrs[a][i];
    red[threadIdx.x] = s; __syncthreads();
    for (int st = 128; st > 0; st >>= 1) {
      if (threadIdx.x < st) red[threadIdx.x] += red[threadIdx.x + st];
      __syncthreads();
    }
    sums[a] = red[0]; __syncthreads();
  }
  if (threadIdx.x == 0) {
    double npos = sums[3] > 1.0 ? sums[3] : 1.0;
    double ns = sums[4] > 1.0 ? sums[4] : 1.0;
    out[0] = (float)(sums[0] / npos + 2.0 * sums[1] / ns + 0.25 * sums[2] / ns);
  }
}

extern "C" void kernel_launch(void* const* d_in, const int* in_sizes, int n_in,
                              void* d_out, int out_size, void* d_ws, size_t ws_size,
                              hipStream_t stream) {
  const float* priors = (const float*)d_in[0];
  const float* dec    = (const float*)d_in[1];
  const float* clsp   = (const float*)d_in[2];
  const float* regp   = (const float*)d_in[3];
  const float* gtb    = (const float*)d_in[4];
  const int*   gtl    = (const int*)d_in[5];
  float* out = (float*)d_out;

  char* w = (char*)d_ws;
  size_t off = 0;
  auto take = [&](size_t bytes) -> char* {
    char* p = w + off;
    off += (bytes + 255) & ~(size_t)255;
    return p;
  };
  float* negsum        = (float*)take((size_t)BS * NP * 4);
  unsigned char* valid = (unsigned char*)take((size_t)BS * NP);
  u64* inboth          = (u64*)take((size_t)BS * NP * 16);
  u64* match           = (u64*)take((size_t)BS * NP * 16);
  const int NBX = (NP + 255) / 256;        // 34
  const int NBLK = NBX * BS;               // 1088
  float* p_vfl = (float*)take((size_t)NBLK * 4);
  float* p_gi  = (float*)take((size_t)NBLK * 4);
  float* p_df  = (float*)take((size_t)NBLK * 4);
  float* p_np  = (float*)take((size_t)NBLK * 4);
  float* p_ns  = (float*)take((size_t)NBLK * 4);
  float* ccostT = (float*)take((size_t)BS * NCLS * NP * 4);   // 87 MB

  hipMemsetAsync(match, 0, (size_t)BS * NP * 16, stream);

  dim3 gridA(NBX, BS);
  k_prep<<<gridA, 256, 0, stream>>>(priors, gtb, clsp, negsum, valid, inboth, ccostT);
  k_assign<<<dim3(BS * NGT), 64, 0, stream>>>(dec, gtb, gtl, valid, inboth, ccostT, match);
  k_postloss<<<gridA, 256, 0, stream>>>(priors, dec, clsp, regp, gtb, gtl,
                                        negsum, valid, inboth, match,
                                        p_vfl, p_gi, p_df, p_np, p_ns);
  k_final<<<1, 256, 0, stream>>>(p_vfl, p_gi, p_df, p_np, p_ns, out, NBLK);
}